// Round 1
// baseline (1250.293 us; speedup 1.0000x reference)
//
#include <hip/hip_runtime.h>
#include <math.h>

// ---------------- problem constants ----------------
constexpr int BATCH   = 8;
constexpr int NUM_CLS = 80;
constexpr int N0 = 19 * 19 * 3;   // 1083  (stride 32)
constexpr int N1 = 38 * 38 * 3;   // 4332  (stride 16)
constexpr int N2 = 76 * 76 * 3;   // 17328 (stride 8)
constexpr int OFF1 = N0;          // 1083
constexpr int OFF2 = N0 + N1;     // 5415
constexpr int NTOT = N0 + N1 + N2; // 22743 per image
constexpr int TOPN = 1000;
constexpr int NSEL = 3 * TOPN;    // 3000 per image
constexpr int MAXDET = 100;
constexpr float MIN_SCORE_F = 0.05f;
constexpr float NMS_THR_F = 0.5f;
constexpr int IMG_MAX = 607;

__device__ __forceinline__ float sigmoidf_(float x) {
    return 1.0f / (1.0f + expf(-x));
}

// ---------------- K1: decode all candidates ----------------
// Writes per-candidate: u64 sort key (raw score bits<<15 | (Nl-n) tiebreak),
// class (as float), clamped int box (as float4).
__global__ __launch_bounds__(256) void k_decode(
    const float* __restrict__ obj0, const float* __restrict__ reg0,
    const float* __restrict__ cls0, const float* __restrict__ anc0,
    const float* __restrict__ obj1, const float* __restrict__ reg1,
    const float* __restrict__ cls1, const float* __restrict__ anc1,
    const float* __restrict__ obj2, const float* __restrict__ reg2,
    const float* __restrict__ cls2, const float* __restrict__ anc2,
    unsigned long long* __restrict__ decKey, float* __restrict__ decC,
    float* __restrict__ decB, int* __restrict__ counters)
{
    if (blockIdx.x == 0 && threadIdx.x < BATCH) counters[threadIdx.x] = 0;
    int idx = blockIdx.x * 256 + threadIdx.x;
    if (idx >= BATCH * NTOT) return;
    int b  = idx / NTOT;
    int na = idx - b * NTOT;

    const float *obj, *reg, *cls, *anc;
    int Nl, n;
    if (na < OFF1)      { obj = obj0; reg = reg0; cls = cls0; anc = anc0; Nl = N0; n = na; }
    else if (na < OFF2) { obj = obj1; reg = reg1; cls = cls1; anc = anc1; Nl = N1; n = na - OFF1; }
    else                { obj = obj2; reg = reg2; cls = cls2; anc = anc2; Nl = N2; n = na - OFF2; }

    size_t bn = (size_t)b * Nl + n;

    float so = sigmoidf_(obj[bn]);

    // argmax over sigmoid(cls), first-occurrence ties (== jnp.argmax)
    const float4* cv = reinterpret_cast<const float4*>(cls + bn * NUM_CLS);
    float best = -1.0f; int bc = 0;
    #pragma unroll 4
    for (int t = 0; t < NUM_CLS / 4; ++t) {
        float4 v = cv[t];
        float s;
        s = sigmoidf_(v.x); if (s > best) { best = s; bc = 4 * t + 0; }
        s = sigmoidf_(v.y); if (s > best) { best = s; bc = 4 * t + 1; }
        s = sigmoidf_(v.z); if (s > best) { best = s; bc = 4 * t + 2; }
        s = sigmoidf_(v.w); if (s > best) { best = s; bc = 4 * t + 3; }
    }
    float score = best * so;

    float4 rv = reinterpret_cast<const float4*>(reg)[bn];
    const float* av = anc + bn * 5;
    float ax = av[0], ay = av[1], aw = av[2], ah = av[3], st = av[4];
    float cx = (sigmoidf_(rv.x) + ax) * st;
    float cy = (sigmoidf_(rv.y) + ay) * st;
    float w  = expf(rv.z) * aw / st;
    float h  = expf(rv.w) * ah / st;
    float x1f = cx - 0.5f * w;
    float y1f = cy - 0.5f * h;
    float x2f = w + x1f;
    float y2f = h + y1f;
    int x1 = (int)x1f, y1 = (int)y1f, x2 = (int)x2f, y2 = (int)y2f; // trunc toward 0
    x1 = (x1 < 0) ? 0 : x1;
    y1 = (y1 < 0) ? 0 : y1;
    x2 = (x2 > IMG_MAX) ? IMG_MAX : x2;
    y2 = (y2 > IMG_MAX) ? IMG_MAX : y2;

    size_t g = (size_t)b * NTOT + na;
    decKey[g] = ((unsigned long long)__float_as_uint(score) << 15) | (unsigned)(Nl - n);
    decC[g] = (float)bc;
    reinterpret_cast<float4*>(decB)[g] =
        make_float4((float)x1, (float)y1, (float)x2, (float)y2);
}

// ---------------- K2: exact top-1000 membership per (image, level) ----------------
__global__ __launch_bounds__(256) void k_select(
    const unsigned long long* __restrict__ decKey, const float* __restrict__ decC,
    const float* __restrict__ decB, float* __restrict__ selS, int* __restrict__ selG,
    float* __restrict__ selC, float* __restrict__ selB, int* __restrict__ counters)
{
    constexpr int BL0 = (N0 + 255) / 256;  // 5
    constexpr int BL1 = (N1 + 255) / 256;  // 17
    constexpr int BL2 = (N2 + 255) / 256;  // 68
    constexpr int BPB = BL0 + BL1 + BL2;   // 90 blocks per image

    int b = blockIdx.x / BPB;
    int r = blockIdx.x % BPB;
    int off, Nl, blk;
    if (r < BL0)            { off = 0;    Nl = N0; blk = r; }
    else if (r < BL0 + BL1) { off = OFF1; Nl = N1; blk = r - BL0; }
    else                    { off = OFF2; Nl = N2; blk = r - BL0 - BL1; }

    const unsigned long long* keys = decKey + (size_t)b * NTOT + off;
    int i = blk * 256 + threadIdx.x;
    unsigned long long ki = (i < Nl) ? keys[i] : ~0ULL;

    int rank = 0;
    __shared__ unsigned long long tile[256];
    int ntiles = (Nl + 255) / 256;
    for (int t0 = 0; t0 < ntiles; ++t0) {
        int j = t0 * 256 + threadIdx.x;
        tile[threadIdx.x] = (j < Nl) ? keys[j] : 0ULL; // 0 never beats a real key
        __syncthreads();
        #pragma unroll 8
        for (int t = 0; t < 256; ++t)
            rank += (tile[t] > ki) ? 1 : 0;
        __syncthreads();
    }

    if (i < Nl && rank < TOPN) {
        int slot = atomicAdd(&counters[b], 1);        // arbitrary order; K3 re-sorts
        size_t g = (size_t)b * NTOT + off + i;
        int o = b * NSEL + slot;
        float s = __uint_as_float((unsigned)(ki >> 15)); // raw score
        selS[o] = (s > MIN_SCORE_F) ? s : -1.0f;         // transformed score
        selG[o] = off + i;                                // global idx = tiebreak
        selC[o] = decC[g];
        reinterpret_cast<float4*>(selB)[o] = reinterpret_cast<const float4*>(decB)[g];
    }
}

// ---------------- K3: global sort of 3000 candidates per image ----------------
__global__ __launch_bounds__(256) void k_rank_all(
    const float* __restrict__ selS, const int* __restrict__ selG,
    const float* __restrict__ selC, const float* __restrict__ selB,
    float* __restrict__ srtS, float* __restrict__ srtC, float* __restrict__ srtB)
{
    constexpr int BPB = (NSEL + 255) / 256; // 12
    int b = blockIdx.x / BPB;
    int blk = blockIdx.x % BPB;
    int i = blk * 256 + threadIdx.x;

    __shared__ unsigned long long keys[NSEL]; // 24 KB
    const float* S = selS + b * NSEL;
    const int*   G = selG + b * NSEL;
    for (int t = threadIdx.x; t < NSEL; t += 256) {
        unsigned u = __float_as_uint(S[t]);
        unsigned m = (u & 0x80000000u) ? ~u : (u | 0x80000000u); // order-preserving map
        keys[t] = ((unsigned long long)m << 16) | (unsigned)(NTOT - G[t]);
    }
    __syncthreads();
    if (i >= NSEL) return;

    unsigned long long ki = keys[i];
    int rank = 0;
    #pragma unroll 8
    for (int j = 0; j < NSEL; ++j)
        rank += (keys[j] > ki) ? 1 : 0;

    int o = b * NSEL + rank;
    srtS[o] = S[i];
    srtC[o] = selC[b * NSEL + i];
    reinterpret_cast<float4*>(srtB)[o] =
        reinterpret_cast<const float4*>(selB)[b * NSEL + i];
}

// ---------------- K4: greedy NMS, one wave per image ----------------
__global__ __launch_bounds__(64) void k_nms(
    const float* __restrict__ srtS, const float* __restrict__ srtC,
    const float* __restrict__ srtB, float* __restrict__ out)
{
    __shared__ float4 bx[NSEL];          // 48000 B
    __shared__ float  area[NSEL];        // 12000 B
    __shared__ unsigned char keep[NSEL]; //  3000 B

    int b = blockIdx.x;
    int lane = threadIdx.x;
    const float*  S  = srtS + b * NSEL;
    const float*  C  = srtC + b * NSEL;
    const float4* Bx = reinterpret_cast<const float4*>(srtB) + (size_t)b * NSEL;

    float* out_s = out + b * MAXDET;
    float* out_c = out + BATCH * MAXDET + b * MAXDET;
    float* out_b = out + 2 * BATCH * MAXDET + (size_t)b * MAXDET * 4;
    for (int t = lane; t < MAXDET; t += 64) { out_s[t] = -1.0f; out_c[t] = -1.0f; }
    for (int t = lane; t < MAXDET * 4; t += 64) out_b[t] = -1.0f;

    for (int t = lane; t < NSEL; t += 64) {
        float4 bb = Bx[t];
        bx[t] = bb;
        area[t] = (bb.z - bb.x) * (bb.w - bb.y);
        keep[t] = (S[t] > MIN_SCORE_F) ? 1 : 0;
    }
    __syncthreads();

    int pos = 0;
    int i = 0;
    while (i < NSEL && pos < MAXDET) {
        // ballot-based scan for the next kept index >= i (uniform across wave)
        int nxt = -1;
        while (i < NSEL) {
            int t = i + lane;
            int kf = (t < NSEL) ? (int)keep[t] : 0;
            unsigned long long m = __ballot(kf != 0);
            if (m != 0ULL) { nxt = i + (__ffsll(m) - 1); break; }
            i += 64;
        }
        if (nxt < 0) break;
        i = nxt;

        float4 bi = bx[i];
        float  ai = area[i];
        if (lane == 0) {
            out_s[pos] = S[i];
            out_c[pos] = C[i];
            out_b[pos * 4 + 0] = bi.x; out_b[pos * 4 + 1] = bi.y;
            out_b[pos * 4 + 2] = bi.z; out_b[pos * 4 + 3] = bi.w;
        }
        pos++;
        if (pos >= MAXDET) break; // later keeps can't affect first 100 slots

        for (int j = i + 1 + lane; j < NSEL; j += 64) {
            if (!keep[j]) continue;
            float4 bj = bx[j];
            float xx1 = fmaxf(bi.x, bj.x);
            float yy1 = fmaxf(bi.y, bj.y);
            float xx2 = fminf(bi.z, bj.z);
            float yy2 = fminf(bi.w, bj.w);
            float inter = fmaxf(xx2 - xx1, 0.0f) * fmaxf(yy2 - yy1, 0.0f);
            float iou = inter / (ai + area[j] - inter);
            if (iou > NMS_THR_F) keep[j] = 0;
        }
        __syncthreads();
        i += 1;
    }
}

// ---------------- host launcher ----------------
extern "C" void kernel_launch(void* const* d_in, const int* in_sizes, int n_in,
                              void* d_out, int out_size, void* d_ws, size_t ws_size,
                              hipStream_t stream) {
    (void)n_in; (void)out_size; (void)ws_size;

    // setup_inputs() dict order: obj0,reg0,cls0,anc0, obj1,... ; detect via cls0 size.
    bool dict = (in_sizes[2] == BATCH * N0 * NUM_CLS); // 693120
    const float *obj[3], *reg[3], *cls[3], *anc[3];
    for (int l = 0; l < 3; ++l) {
        obj[l] = (const float*)d_in[dict ? 4 * l + 0 : l];
        reg[l] = (const float*)d_in[dict ? 4 * l + 1 : 3 + l];
        cls[l] = (const float*)d_in[dict ? 4 * l + 2 : 6 + l];
        anc[l] = (const float*)d_in[dict ? 4 * l + 3 : 9 + l];
    }

    char* ws = (char*)d_ws;
    size_t off = 0;
    auto take = [&](size_t bytes) -> void* {
        void* p = ws + off;
        off += (bytes + 255) & ~(size_t)255;
        return p;
    };
    int*                 counters = (int*)take(BATCH * sizeof(int));
    unsigned long long*  decKey   = (unsigned long long*)take((size_t)BATCH * NTOT * 8);
    float*               decC     = (float*)take((size_t)BATCH * NTOT * 4);
    float*               decB     = (float*)take((size_t)BATCH * NTOT * 16);
    float*               selS     = (float*)take((size_t)BATCH * NSEL * 4);
    int*                 selG     = (int*)take((size_t)BATCH * NSEL * 4);
    float*               selC     = (float*)take((size_t)BATCH * NSEL * 4);
    float*               selB     = (float*)take((size_t)BATCH * NSEL * 16);
    float*               srtS     = (float*)take((size_t)BATCH * NSEL * 4);
    float*               srtC     = (float*)take((size_t)BATCH * NSEL * 4);
    float*               srtB     = (float*)take((size_t)BATCH * NSEL * 16);

    int totalDec = BATCH * NTOT; // 181944
    k_decode<<<(totalDec + 255) / 256, 256, 0, stream>>>(
        obj[0], reg[0], cls[0], anc[0],
        obj[1], reg[1], cls[1], anc[1],
        obj[2], reg[2], cls[2], anc[2],
        decKey, decC, decB, counters);

    k_select<<<BATCH * 90, 256, 0, stream>>>(decKey, decC, decB,
                                             selS, selG, selC, selB, counters);

    k_rank_all<<<BATCH * 12, 256, 0, stream>>>(selS, selG, selC, selB,
                                               srtS, srtC, srtB);

    k_nms<<<BATCH, 64, 0, stream>>>(srtS, srtC, srtB, (float*)d_out);
}

// Round 2
// 465.737 us; speedup vs baseline: 2.6846x; 2.6846x over previous
//
#include <hip/hip_runtime.h>
#include <math.h>

// ---------------- problem constants ----------------
constexpr int BATCH   = 8;
constexpr int NUM_CLS = 80;
constexpr int N0 = 19 * 19 * 3;   // 1083  (stride 32)
constexpr int N1 = 38 * 38 * 3;   // 4332  (stride 16)
constexpr int N2 = 76 * 76 * 3;   // 17328 (stride 8)
constexpr int OFF1 = N0;          // 1083
constexpr int OFF2 = N0 + N1;     // 5415
constexpr int NTOT = N0 + N1 + N2; // 22743 per image
constexpr int TOPN = 1000;
constexpr int NSEL = 3 * TOPN;    // 3000 per image
constexpr int MAXDET = 100;
constexpr float MIN_SCORE_F = 0.05f;
constexpr float NMS_THR_F = 0.5f;
constexpr int IMG_MAX = 607;

__device__ __forceinline__ float sigmoidf_(float x) {
    return 1.0f / (1.0f + expf(-x));
}

// ---------------- K1: decode all candidates ----------------
// Per-candidate: u64 sort key (score_bits<<15 | (Nl-n) tiebreak == lower-index-
// first within a level), class (float), clamped int box (float4).
__global__ __launch_bounds__(256) void k_decode(
    const float* __restrict__ obj0, const float* __restrict__ reg0,
    const float* __restrict__ cls0, const float* __restrict__ anc0,
    const float* __restrict__ obj1, const float* __restrict__ reg1,
    const float* __restrict__ cls1, const float* __restrict__ anc1,
    const float* __restrict__ obj2, const float* __restrict__ reg2,
    const float* __restrict__ cls2, const float* __restrict__ anc2,
    unsigned long long* __restrict__ decKey, float* __restrict__ decC,
    float* __restrict__ decB, int* __restrict__ counters)
{
    if (blockIdx.x == 0 && threadIdx.x < BATCH) counters[threadIdx.x] = 0;
    int idx = blockIdx.x * 256 + threadIdx.x;
    if (idx >= BATCH * NTOT) return;
    int b  = idx / NTOT;
    int na = idx - b * NTOT;

    const float *obj, *reg, *cls, *anc;
    int Nl, n;
    if (na < OFF1)      { obj = obj0; reg = reg0; cls = cls0; anc = anc0; Nl = N0; n = na; }
    else if (na < OFF2) { obj = obj1; reg = reg1; cls = cls1; anc = anc1; Nl = N1; n = na - OFF1; }
    else                { obj = obj2; reg = reg2; cls = cls2; anc = anc2; Nl = N2; n = na - OFF2; }

    size_t bn = (size_t)b * Nl + n;

    float so = sigmoidf_(obj[bn]);

    // argmax over sigmoid(cls), first-occurrence ties (== jnp.argmax)
    const float4* cv = reinterpret_cast<const float4*>(cls + bn * NUM_CLS);
    float best = -1.0f; int bc = 0;
    #pragma unroll 4
    for (int t = 0; t < NUM_CLS / 4; ++t) {
        float4 v = cv[t];
        float s;
        s = sigmoidf_(v.x); if (s > best) { best = s; bc = 4 * t + 0; }
        s = sigmoidf_(v.y); if (s > best) { best = s; bc = 4 * t + 1; }
        s = sigmoidf_(v.z); if (s > best) { best = s; bc = 4 * t + 2; }
        s = sigmoidf_(v.w); if (s > best) { best = s; bc = 4 * t + 3; }
    }
    float score = best * so;

    float4 rv = reinterpret_cast<const float4*>(reg)[bn];
    const float* av = anc + bn * 5;
    float ax = av[0], ay = av[1], aw = av[2], ah = av[3], st = av[4];
    float cx = (sigmoidf_(rv.x) + ax) * st;
    float cy = (sigmoidf_(rv.y) + ay) * st;
    float w  = expf(rv.z) * aw / st;
    float h  = expf(rv.w) * ah / st;
    float x1f = cx - 0.5f * w;
    float y1f = cy - 0.5f * h;
    float x2f = w + x1f;
    float y2f = h + y1f;
    int x1 = (int)x1f, y1 = (int)y1f, x2 = (int)x2f, y2 = (int)y2f; // trunc toward 0
    x1 = (x1 < 0) ? 0 : x1;
    y1 = (y1 < 0) ? 0 : y1;
    x2 = (x2 > IMG_MAX) ? IMG_MAX : x2;
    y2 = (y2 > IMG_MAX) ? IMG_MAX : y2;

    size_t g = (size_t)b * NTOT + na;
    decKey[g] = ((unsigned long long)__float_as_uint(score) << 15) | (unsigned)(Nl - n);
    decC[g] = (float)bc;
    reinterpret_cast<float4*>(decB)[g] =
        make_float4((float)x1, (float)y1, (float)x2, (float)y2);
}

// ---------------- K2: exact top-1000 per (image, level) via histogram select ----
// bucket = key>>32 = score_bits>>17, in [0, 8128]. Buckets strictly above the
// 1000th element's bucket are all selected; boundary bucket resolved by exact
// rank among its members (small M). Guaranteed-correct O(N^2) fallback if the
// boundary bucket overflows the LDS tie list (never with this data).
constexpr int NBIN = 8192;
constexpr int TIE_CAP = 4096;

__global__ __launch_bounds__(1024) void k_select(
    const unsigned long long* __restrict__ decKey, const float* __restrict__ decC,
    const float* __restrict__ decB, float* __restrict__ selS, int* __restrict__ selG,
    float* __restrict__ selC, float* __restrict__ selB, int* __restrict__ counters)
{
    __shared__ unsigned long long tiekeys[TIE_CAP]; // 32 KB; aliased as hist first
    __shared__ int tieidx[TIE_CAP];                 // 16 KB
    __shared__ unsigned chunksum[NBIN / 64];        // 512 B
    __shared__ int sBstar; __shared__ unsigned sCntHi; __shared__ int sM;

    unsigned* hist = reinterpret_cast<unsigned*>(tiekeys); // 8192 bins

    int b   = blockIdx.x / 3;
    int lvl = blockIdx.x % 3;
    int off = (lvl == 0) ? 0 : (lvl == 1) ? OFF1 : OFF2;
    int Nl  = (lvl == 0) ? N0 : (lvl == 1) ? N1 : N2;
    int tid = threadIdx.x;

    const unsigned long long* keys = decKey + (size_t)b * NTOT + off;

    for (int t = tid; t < NBIN; t += 1024) hist[t] = 0;
    if (tid == 0) sM = 0;
    __syncthreads();

    for (int t = tid; t < Nl; t += 1024) {
        unsigned bkt = (unsigned)(keys[t] >> 32);
        atomicAdd(&hist[bkt], 1u);
    }
    __syncthreads();

    if (tid < NBIN / 64) {
        unsigned s = 0;
        for (int j = 0; j < 64; ++j) s += hist[tid * 64 + j];
        chunksum[tid] = s;
    }
    __syncthreads();
    if (tid == 0) {
        unsigned running = 0; int c = NBIN / 64 - 1;
        for (; c >= 0; --c) {
            if (running + chunksum[c] >= (unsigned)TOPN) break;
            running += chunksum[c];
        }
        int B = 0;
        for (int bkt = c * 64 + 63; bkt >= c * 64; --bkt) {
            unsigned h = hist[bkt];
            if (running + h >= (unsigned)TOPN) { B = bkt; break; }
            running += h;
        }
        sBstar = B; sCntHi = running;
    }
    __syncthreads();
    int Bstar = sBstar;
    unsigned cntHi = sCntHi;
    __syncthreads(); // hist dead from here; tiekeys aliases it

    auto emit = [&](int t) {
        int slot = atomicAdd(&counters[b], 1);
        size_t g = (size_t)b * NTOT + off + t;
        int o = b * NSEL + slot;
        float s = __uint_as_float((unsigned)(decKey[g] >> 15));
        selS[o] = (s > MIN_SCORE_F) ? s : -1.0f;
        selG[o] = off + t;
        selC[o] = decC[g];
        reinterpret_cast<float4*>(selB)[o] = reinterpret_cast<const float4*>(decB)[g];
    };

    for (int t = tid; t < Nl; t += 1024) {
        unsigned long long k = keys[t];
        unsigned bkt = (unsigned)(k >> 32);
        if ((int)bkt > Bstar) {
            emit(t);
        } else if ((int)bkt == Bstar) {
            int m = atomicAdd(&sM, 1);
            if (m < TIE_CAP) { tiekeys[m] = k; tieidx[m] = t; }
        }
    }
    __syncthreads();

    int M = sM;
    int need = TOPN - (int)cntHi; // >= 1
    if (M <= TIE_CAP) {
        for (int m = tid; m < M; m += 1024) {
            unsigned long long k = tiekeys[m];
            int r = 0;
            for (int j = 0; j < M; ++j) r += (tiekeys[j] > k) ? 1 : 0;
            if (r < need) emit(tieidx[m]);
        }
    } else {
        // never-triggered exact fallback
        for (int t = tid; t < Nl; t += 1024) {
            unsigned long long k = keys[t];
            if ((int)(unsigned)(k >> 32) != Bstar) continue;
            int r = 0;
            for (int j = 0; j < Nl; ++j) r += (keys[j] > k) ? 1 : 0;
            if (r < (int)cntHi + need) emit(t);
        }
    }
}

// ---------------- K3: global sort of 3000 candidates per image ----------------
__global__ __launch_bounds__(256) void k_rank_all(
    const float* __restrict__ selS, const int* __restrict__ selG,
    const float* __restrict__ selC, const float* __restrict__ selB,
    float* __restrict__ srtS, float* __restrict__ srtC, float* __restrict__ srtB)
{
    constexpr int BPB = (NSEL + 255) / 256; // 12
    int b = blockIdx.x / BPB;
    int blk = blockIdx.x % BPB;
    int i = blk * 256 + threadIdx.x;

    __shared__ unsigned long long keys[NSEL]; // 24 KB
    const float* S = selS + b * NSEL;
    const int*   G = selG + b * NSEL;
    for (int t = threadIdx.x; t < NSEL; t += 256) {
        unsigned u = __float_as_uint(S[t]);
        unsigned m = (u & 0x80000000u) ? ~u : (u | 0x80000000u); // order-preserving map
        keys[t] = ((unsigned long long)m << 16) | (unsigned)(NTOT - G[t]);
    }
    __syncthreads();
    if (i >= NSEL) return;

    unsigned long long ki = keys[i];
    int rank = 0;
    #pragma unroll 8
    for (int j = 0; j < NSEL; ++j)
        rank += (keys[j] > ki) ? 1 : 0;

    int o = b * NSEL + rank;
    srtS[o] = S[i];
    srtC[o] = selC[b * NSEL + i];
    reinterpret_cast<float4*>(srtB)[o] =
        reinterpret_cast<const float4*>(selB)[b * NSEL + i];
}

// ---------------- K4: greedy NMS, register-resident, 256 thr/image -----------
__global__ __launch_bounds__(256) void k_nms(
    const float* __restrict__ srtS, const float* __restrict__ srtC,
    const float* __restrict__ srtB, float* __restrict__ out)
{
    constexpr int PERT = (NSEL + 255) / 256; // 12 candidates per thread
    __shared__ float4 bx[NSEL];      // 48000 B
    __shared__ int    keepL[NSEL];   // 12000 B
    __shared__ int    keptIdx[MAXDET];

    int b = blockIdx.x;
    int tid = threadIdx.x;
    const float*  S  = srtS + b * NSEL;
    const float4* Bx = reinterpret_cast<const float4*>(srtB) + (size_t)b * NSEL;

    float4 rb[PERT];
    float  ra[PERT];
    bool   rk[PERT];
    #pragma unroll
    for (int k = 0; k < PERT; ++k) {
        int j = tid + k * 256;
        if (j < NSEL) {
            float4 bb = Bx[j];
            float  s  = S[j];
            rb[k] = bb;
            ra[k] = (bb.z - bb.x) * (bb.w - bb.y);
            rk[k] = (s > MIN_SCORE_F);
            bx[j] = bb;
            keepL[j] = rk[k] ? 1 : 0;
        } else rk[k] = false;
    }
    __syncthreads();

    int i = 0, pos = 0;
    while (true) {
        // scan for next kept index >= i (all waves identical, wave-uniform i)
        int nxt = -1;
        while (i < NSEL) {
            int t = i + (tid & 63);
            int kf = (t < NSEL) ? keepL[t] : 0;
            unsigned long long m = __ballot(kf != 0);
            if (m != 0ULL) { nxt = i + (__ffsll(m) - 1); break; }
            i += 64;
        }
        if (nxt < 0) break;
        i = nxt;

        float4 bi = bx[i];
        float  ai = (bi.z - bi.x) * (bi.w - bi.y);
        if (tid == 0) keptIdx[pos] = i;
        pos++;
        if (pos >= MAXDET) break;

        #pragma unroll
        for (int k = 0; k < PERT; ++k) {
            int j = tid + k * 256;
            if (rk[k] && j > i) {
                float4 bj = rb[k];
                float xx1 = fmaxf(bi.x, bj.x);
                float yy1 = fmaxf(bi.y, bj.y);
                float xx2 = fminf(bi.z, bj.z);
                float yy2 = fminf(bi.w, bj.w);
                float inter = fmaxf(xx2 - xx1, 0.0f) * fmaxf(yy2 - yy1, 0.0f);
                float iou = inter / (ai + ra[k] - inter);
                if (iou > NMS_THR_F) { rk[k] = false; keepL[j] = 0; }
            }
        }
        __syncthreads();
        i += 1;
    }

    __syncthreads();
    float* out_s = out + b * MAXDET;
    float* out_c = out + BATCH * MAXDET + b * MAXDET;
    float* out_b = out + 2 * BATCH * MAXDET + (size_t)b * MAXDET * 4;
    for (int t = tid; t < MAXDET; t += 256) {
        if (t < pos) {
            int ki = keptIdx[t];
            float4 bb = bx[ki];
            out_s[t] = S[ki];
            out_c[t] = srtC[b * NSEL + ki];
            out_b[t * 4 + 0] = bb.x; out_b[t * 4 + 1] = bb.y;
            out_b[t * 4 + 2] = bb.z; out_b[t * 4 + 3] = bb.w;
        } else {
            out_s[t] = -1.0f; out_c[t] = -1.0f;
            out_b[t * 4 + 0] = -1.0f; out_b[t * 4 + 1] = -1.0f;
            out_b[t * 4 + 2] = -1.0f; out_b[t * 4 + 3] = -1.0f;
        }
    }
}

// ---------------- host launcher ----------------
extern "C" void kernel_launch(void* const* d_in, const int* in_sizes, int n_in,
                              void* d_out, int out_size, void* d_ws, size_t ws_size,
                              hipStream_t stream) {
    (void)n_in; (void)out_size; (void)ws_size;

    bool dict = (in_sizes[2] == BATCH * N0 * NUM_CLS); // 693120
    const float *obj[3], *reg[3], *cls[3], *anc[3];
    for (int l = 0; l < 3; ++l) {
        obj[l] = (const float*)d_in[dict ? 4 * l + 0 : l];
        reg[l] = (const float*)d_in[dict ? 4 * l + 1 : 3 + l];
        cls[l] = (const float*)d_in[dict ? 4 * l + 2 : 6 + l];
        anc[l] = (const float*)d_in[dict ? 4 * l + 3 : 9 + l];
    }

    char* ws = (char*)d_ws;
    size_t off = 0;
    auto take = [&](size_t bytes) -> void* {
        void* p = ws + off;
        off += (bytes + 255) & ~(size_t)255;
        return p;
    };
    int*                 counters = (int*)take(BATCH * sizeof(int));
    unsigned long long*  decKey   = (unsigned long long*)take((size_t)BATCH * NTOT * 8);
    float*               decC     = (float*)take((size_t)BATCH * NTOT * 4);
    float*               decB     = (float*)take((size_t)BATCH * NTOT * 16);
    float*               selS     = (float*)take((size_t)BATCH * NSEL * 4);
    int*                 selG     = (int*)take((size_t)BATCH * NSEL * 4);
    float*               selC     = (float*)take((size_t)BATCH * NSEL * 4);
    float*               selB     = (float*)take((size_t)BATCH * NSEL * 16);
    float*               srtS     = (float*)take((size_t)BATCH * NSEL * 4);
    float*               srtC     = (float*)take((size_t)BATCH * NSEL * 4);
    float*               srtB     = (float*)take((size_t)BATCH * NSEL * 16);

    int totalDec = BATCH * NTOT; // 181944
    k_decode<<<(totalDec + 255) / 256, 256, 0, stream>>>(
        obj[0], reg[0], cls[0], anc[0],
        obj[1], reg[1], cls[1], anc[1],
        obj[2], reg[2], cls[2], anc[2],
        decKey, decC, decB, counters);

    k_select<<<BATCH * 3, 1024, 0, stream>>>(decKey, decC, decB,
                                             selS, selG, selC, selB, counters);

    k_rank_all<<<BATCH * 12, 256, 0, stream>>>(selS, selG, selC, selB,
                                               srtS, srtC, srtB);

    k_nms<<<BATCH, 256, 0, stream>>>(srtS, srtC, srtB, (float*)d_out);
}

// Round 3
// 352.211 us; speedup vs baseline: 3.5498x; 1.3223x over previous
//
#include <hip/hip_runtime.h>
#include <math.h>

// ---------------- problem constants ----------------
constexpr int BATCH   = 8;
constexpr int NUM_CLS = 80;
constexpr int N0 = 19 * 19 * 3;   // 1083  (stride 32)
constexpr int N1 = 38 * 38 * 3;   // 4332  (stride 16)
constexpr int N2 = 76 * 76 * 3;   // 17328 (stride 8)
constexpr int OFF1 = N0;          // 1083
constexpr int OFF2 = N0 + N1;     // 5415
constexpr int NTOT = N0 + N1 + N2; // 22743 per image
constexpr int TOPN = 1000;
constexpr int NSEL = 3 * TOPN;    // 3000 per image
constexpr int MAXDET = 100;
constexpr float MIN_SCORE_F = 0.05f;
constexpr float NMS_THR_F = 0.5f;
constexpr int IMG_MAX = 607;
constexpr int WPR = (NSEL + 63) / 64; // 47 u64 words per mask row

__device__ __forceinline__ float sigmoidf_(float x) {
    return 1.0f / (1.0f + expf(-x));
}

// ---------------- K1: decode all candidates ----------------
__global__ __launch_bounds__(256) void k_decode(
    const float* __restrict__ obj0, const float* __restrict__ reg0,
    const float* __restrict__ cls0, const float* __restrict__ anc0,
    const float* __restrict__ obj1, const float* __restrict__ reg1,
    const float* __restrict__ cls1, const float* __restrict__ anc1,
    const float* __restrict__ obj2, const float* __restrict__ reg2,
    const float* __restrict__ cls2, const float* __restrict__ anc2,
    unsigned long long* __restrict__ decKey, float* __restrict__ decC,
    float* __restrict__ decB, int* __restrict__ counters)
{
    if (blockIdx.x == 0 && threadIdx.x < BATCH) counters[threadIdx.x] = 0;
    int idx = blockIdx.x * 256 + threadIdx.x;
    if (idx >= BATCH * NTOT) return;
    int b  = idx / NTOT;
    int na = idx - b * NTOT;

    const float *obj, *reg, *cls, *anc;
    int Nl, n;
    if (na < OFF1)      { obj = obj0; reg = reg0; cls = cls0; anc = anc0; Nl = N0; n = na; }
    else if (na < OFF2) { obj = obj1; reg = reg1; cls = cls1; anc = anc1; Nl = N1; n = na - OFF1; }
    else                { obj = obj2; reg = reg2; cls = cls2; anc = anc2; Nl = N2; n = na - OFF2; }

    size_t bn = (size_t)b * Nl + n;

    float so = sigmoidf_(obj[bn]);

    const float4* cv = reinterpret_cast<const float4*>(cls + bn * NUM_CLS);
    float best = -1.0f; int bc = 0;
    #pragma unroll 4
    for (int t = 0; t < NUM_CLS / 4; ++t) {
        float4 v = cv[t];
        float s;
        s = sigmoidf_(v.x); if (s > best) { best = s; bc = 4 * t + 0; }
        s = sigmoidf_(v.y); if (s > best) { best = s; bc = 4 * t + 1; }
        s = sigmoidf_(v.z); if (s > best) { best = s; bc = 4 * t + 2; }
        s = sigmoidf_(v.w); if (s > best) { best = s; bc = 4 * t + 3; }
    }
    float score = best * so;

    float4 rv = reinterpret_cast<const float4*>(reg)[bn];
    const float* av = anc + bn * 5;
    float ax = av[0], ay = av[1], aw = av[2], ah = av[3], st = av[4];
    float cx = (sigmoidf_(rv.x) + ax) * st;
    float cy = (sigmoidf_(rv.y) + ay) * st;
    float w  = expf(rv.z) * aw / st;
    float h  = expf(rv.w) * ah / st;
    float x1f = cx - 0.5f * w;
    float y1f = cy - 0.5f * h;
    float x2f = w + x1f;
    float y2f = h + y1f;
    int x1 = (int)x1f, y1 = (int)y1f, x2 = (int)x2f, y2 = (int)y2f;
    x1 = (x1 < 0) ? 0 : x1;
    y1 = (y1 < 0) ? 0 : y1;
    x2 = (x2 > IMG_MAX) ? IMG_MAX : x2;
    y2 = (y2 > IMG_MAX) ? IMG_MAX : y2;

    size_t g = (size_t)b * NTOT + na;
    decKey[g] = ((unsigned long long)__float_as_uint(score) << 15) | (unsigned)(Nl - n);
    decC[g] = (float)bc;
    reinterpret_cast<float4*>(decB)[g] =
        make_float4((float)x1, (float)y1, (float)x2, (float)y2);
}

// ---------------- K2: exact top-1000 per (image, level) via histogram select ----
constexpr int NBIN = 8192;
constexpr int TIE_CAP = 4096;

__global__ __launch_bounds__(1024) void k_select(
    const unsigned long long* __restrict__ decKey, const float* __restrict__ decC,
    const float* __restrict__ decB, float* __restrict__ selS, int* __restrict__ selG,
    float* __restrict__ selC, float* __restrict__ selB, int* __restrict__ counters)
{
    __shared__ unsigned long long tiekeys[TIE_CAP];
    __shared__ int tieidx[TIE_CAP];
    __shared__ unsigned chunksum[NBIN / 64];
    __shared__ int sBstar; __shared__ unsigned sCntHi; __shared__ int sM;

    unsigned* hist = reinterpret_cast<unsigned*>(tiekeys);

    int b   = blockIdx.x / 3;
    int lvl = blockIdx.x % 3;
    int off = (lvl == 0) ? 0 : (lvl == 1) ? OFF1 : OFF2;
    int Nl  = (lvl == 0) ? N0 : (lvl == 1) ? N1 : N2;
    int tid = threadIdx.x;

    const unsigned long long* keys = decKey + (size_t)b * NTOT + off;

    for (int t = tid; t < NBIN; t += 1024) hist[t] = 0;
    if (tid == 0) sM = 0;
    __syncthreads();

    for (int t = tid; t < Nl; t += 1024) {
        unsigned bkt = (unsigned)(keys[t] >> 32);
        atomicAdd(&hist[bkt], 1u);
    }
    __syncthreads();

    if (tid < NBIN / 64) {
        unsigned s = 0;
        for (int j = 0; j < 64; ++j) s += hist[tid * 64 + j];
        chunksum[tid] = s;
    }
    __syncthreads();
    if (tid == 0) {
        unsigned running = 0; int c = NBIN / 64 - 1;
        for (; c >= 0; --c) {
            if (running + chunksum[c] >= (unsigned)TOPN) break;
            running += chunksum[c];
        }
        int B = 0;
        for (int bkt = c * 64 + 63; bkt >= c * 64; --bkt) {
            unsigned h = hist[bkt];
            if (running + h >= (unsigned)TOPN) { B = bkt; break; }
            running += h;
        }
        sBstar = B; sCntHi = running;
    }
    __syncthreads();
    int Bstar = sBstar;
    unsigned cntHi = sCntHi;
    __syncthreads();

    auto emit = [&](int t) {
        int slot = atomicAdd(&counters[b], 1);
        size_t g = (size_t)b * NTOT + off + t;
        int o = b * NSEL + slot;
        float s = __uint_as_float((unsigned)(decKey[g] >> 15));
        selS[o] = (s > MIN_SCORE_F) ? s : -1.0f;
        selG[o] = off + t;
        selC[o] = decC[g];
        reinterpret_cast<float4*>(selB)[o] = reinterpret_cast<const float4*>(decB)[g];
    };

    for (int t = tid; t < Nl; t += 1024) {
        unsigned long long k = keys[t];
        unsigned bkt = (unsigned)(k >> 32);
        if ((int)bkt > Bstar) {
            emit(t);
        } else if ((int)bkt == Bstar) {
            int m = atomicAdd(&sM, 1);
            if (m < TIE_CAP) { tiekeys[m] = k; tieidx[m] = t; }
        }
    }
    __syncthreads();

    int M = sM;
    int need = TOPN - (int)cntHi;
    if (M <= TIE_CAP) {
        for (int m = tid; m < M; m += 1024) {
            unsigned long long k = tiekeys[m];
            int r = 0;
            for (int j = 0; j < M; ++j) r += (tiekeys[j] > k) ? 1 : 0;
            if (r < need) emit(tieidx[m]);
        }
    } else {
        for (int t = tid; t < Nl; t += 1024) {
            unsigned long long k = keys[t];
            if ((int)(unsigned)(k >> 32) != Bstar) continue;
            int r = 0;
            for (int j = 0; j < Nl; ++j) r += (keys[j] > k) ? 1 : 0;
            if (r < (int)cntHi + need) emit(t);
        }
    }
}

// ---------------- K3: global sort of 3000 candidates per image ----------------
__global__ __launch_bounds__(256) void k_rank_all(
    const float* __restrict__ selS, const int* __restrict__ selG,
    const float* __restrict__ selC, const float* __restrict__ selB,
    float* __restrict__ srtS, float* __restrict__ srtC, float* __restrict__ srtB)
{
    constexpr int BPB = (NSEL + 255) / 256; // 12
    int b = blockIdx.x / BPB;
    int blk = blockIdx.x % BPB;
    int i = blk * 256 + threadIdx.x;

    __shared__ unsigned long long keys[NSEL]; // 24 KB
    const float* S = selS + b * NSEL;
    const int*   G = selG + b * NSEL;
    for (int t = threadIdx.x; t < NSEL; t += 256) {
        unsigned u = __float_as_uint(S[t]);
        unsigned m = (u & 0x80000000u) ? ~u : (u | 0x80000000u);
        keys[t] = ((unsigned long long)m << 16) | (unsigned)(NTOT - G[t]);
    }
    __syncthreads();
    if (i >= NSEL) return;

    unsigned long long ki = keys[i];
    int rank = 0;
    #pragma unroll 8
    for (int j = 0; j < NSEL; ++j)
        rank += (keys[j] > ki) ? 1 : 0;

    int o = b * NSEL + rank;
    srtS[o] = S[i];
    srtC[o] = selC[b * NSEL + i];
    reinterpret_cast<float4*>(srtB)[o] =
        reinterpret_cast<const float4*>(selB)[b * NSEL + i];
}

// ---------------- K4a: pairwise suppression bitmask precompute ---------------
// Block = (image, 64-row tile). Lane owns row i = tile*64 + (tid&63); wave wv
// owns words w = wv + 4k. All lanes iterate the SAME j inside a word -> pure
// LDS broadcast, conflict-free. mask bit j set iff (j > i) && IoU > 0.5.
// Division-free compare is exact: inter/union are exact ints < 2^20 in fp32.
__global__ __launch_bounds__(256) void k_iou(
    const float* __restrict__ srtB, unsigned long long* __restrict__ gmask)
{
    constexpr int TPB = (NSEL + 63) / 64; // 47 row-tiles per image
    __shared__ float4 bxs[NSEL]; // 48 KB
    int b    = blockIdx.x / TPB;
    int tile = blockIdx.x % TPB;
    int tid  = threadIdx.x;
    const float4* Bx = reinterpret_cast<const float4*>(srtB) + (size_t)b * NSEL;
    for (int t = tid; t < NSEL; t += 256) bxs[t] = Bx[t];
    __syncthreads();

    int lane = tid & 63;
    int wv   = tid >> 6;
    int i    = tile * 64 + lane;
    bool rowOk = (i < NSEL);
    float4 bi = rowOk ? bxs[i] : make_float4(0.f, 0.f, 0.f, 0.f);
    float  ai = (bi.z - bi.x) * (bi.w - bi.y);
    unsigned long long* grow = gmask + ((size_t)b * NSEL + (rowOk ? i : 0)) * WPR;

    for (int k = 0; k < 12; ++k) {
        int w = wv + 4 * k;
        if (w >= WPR) break;
        int jbase = w * 64;

        // bits with j <= i or j >= NSEL are forced to 0
        int th = i - jbase;
        unsigned long long kmask =
            (th < 0) ? ~0ull : (th >= 63 ? 0ull : (~0ull << (th + 1)));
        int rem = NSEL - jbase;
        if (rem < 64) kmask &= (1ull << rem) - 1ull;

        unsigned long long m = 0ull;
        if (__any(kmask != 0ull)) {
            #pragma unroll 8
            for (int bit = 0; bit < 64; ++bit) {
                int j = jbase + bit;
                if (j >= NSEL) break; // uniform
                float4 bj = bxs[j];   // uniform broadcast
                float aj = (bj.z - bj.x) * (bj.w - bj.y);
                float xx1 = fmaxf(bi.x, bj.x);
                float yy1 = fmaxf(bi.y, bj.y);
                float xx2 = fminf(bi.z, bj.z);
                float yy2 = fminf(bi.w, bj.w);
                float inter = fmaxf(xx2 - xx1, 0.0f) * fmaxf(yy2 - yy1, 0.0f);
                float uni = ai + aj - inter;
                bool sup = (inter > 0.5f * uni) && (inter > 0.0f);
                if (sup) m |= (1ull << bit);
            }
            m &= kmask;
        }
        if (rowOk) grow[w] = m;
    }
}

// ---------------- K4b: greedy resolve, one block per image -------------------
// Lane l of wave 0 owns bitmap word l (removed/valid) in registers. Per kept
// box: ballot over words -> shfl -> ffs -> one LDS (or global) mask-row read
// -> register OR. No barriers inside the loop; skips are free.
constexpr int RTILE = 256;

__global__ __launch_bounds__(256) void k_resolve(
    const float* __restrict__ srtS, const float* __restrict__ srtC,
    const float* __restrict__ srtB, const unsigned long long* __restrict__ gmask,
    float* __restrict__ out)
{
    __shared__ unsigned long long tileM[RTILE * WPR]; // 94.0 KB
    __shared__ unsigned long long validLds[WPR];
    __shared__ int keptIdx[MAXDET];
    __shared__ int sPos;

    int b = blockIdx.x, tid = threadIdx.x;
    const unsigned long long* gm = gmask + (size_t)b * NSEL * WPR;
    const float* S = srtS + b * NSEL;

    for (int t = tid; t < RTILE * WPR; t += 256) tileM[t] = gm[t];

    // build valid bitmap: wave w's ballot at iteration k covers word k*4+w
    for (int k = 0; k < 12; ++k) {
        int j = k * 256 + tid;
        float s = (j < NSEL) ? S[j] : -1.0f;
        unsigned long long bal = __ballot(s > MIN_SCORE_F);
        int wIdx = k * 4 + (tid >> 6);
        if ((tid & 63) == 0 && wIdx < WPR) validLds[wIdx] = bal;
    }
    __syncthreads();

    if (tid < 64) {
        int lane = tid;
        unsigned long long validw = (lane < WPR) ? validLds[lane] : 0ull;
        unsigned long long removed = 0ull;
        int pos = 0;
        int curw = 0;
        while (true) {
            unsigned long long avail = validw & ~removed;
            unsigned long long bal = __ballot(lane >= curw && avail != 0ull);
            if (bal == 0ull) break;
            int fw = __ffsll(bal) - 1;
            unsigned long long wbits = __shfl(avail, fw);
            int bit = __ffsll(wbits) - 1;
            int i = fw * 64 + bit;
            if (lane == 0) keptIdx[pos] = i;
            pos++;
            if (pos >= MAXDET) break;
            if (lane == fw) validw &= ~(1ull << bit);
            unsigned long long m = 0ull;
            if (lane < WPR)
                m = (i < RTILE) ? tileM[i * WPR + lane]
                                : gm[(size_t)i * WPR + lane];
            removed |= m;
            curw = fw;
        }
        if (lane == 0) sPos = pos;
    }
    __syncthreads();

    int pos = sPos;
    const float*  C  = srtC + b * NSEL;
    const float4* Bx = reinterpret_cast<const float4*>(srtB) + (size_t)b * NSEL;
    float* out_s = out + b * MAXDET;
    float* out_c = out + BATCH * MAXDET + b * MAXDET;
    float* out_b = out + 2 * BATCH * MAXDET + (size_t)b * MAXDET * 4;
    for (int t = tid; t < MAXDET; t += 256) {
        if (t < pos) {
            int ki = keptIdx[t];
            float4 bb = Bx[ki];
            out_s[t] = S[ki];
            out_c[t] = C[ki];
            out_b[t * 4 + 0] = bb.x; out_b[t * 4 + 1] = bb.y;
            out_b[t * 4 + 2] = bb.z; out_b[t * 4 + 3] = bb.w;
        } else {
            out_s[t] = -1.0f; out_c[t] = -1.0f;
            out_b[t * 4 + 0] = -1.0f; out_b[t * 4 + 1] = -1.0f;
            out_b[t * 4 + 2] = -1.0f; out_b[t * 4 + 3] = -1.0f;
        }
    }
}

// ---------------- host launcher ----------------
extern "C" void kernel_launch(void* const* d_in, const int* in_sizes, int n_in,
                              void* d_out, int out_size, void* d_ws, size_t ws_size,
                              hipStream_t stream) {
    (void)n_in; (void)out_size; (void)ws_size;

    bool dict = (in_sizes[2] == BATCH * N0 * NUM_CLS); // 693120
    const float *obj[3], *reg[3], *cls[3], *anc[3];
    for (int l = 0; l < 3; ++l) {
        obj[l] = (const float*)d_in[dict ? 4 * l + 0 : l];
        reg[l] = (const float*)d_in[dict ? 4 * l + 1 : 3 + l];
        cls[l] = (const float*)d_in[dict ? 4 * l + 2 : 6 + l];
        anc[l] = (const float*)d_in[dict ? 4 * l + 3 : 9 + l];
    }

    char* ws = (char*)d_ws;
    size_t off = 0;
    auto take = [&](size_t bytes) -> void* {
        void* p = ws + off;
        off += (bytes + 255) & ~(size_t)255;
        return p;
    };
    int*                 counters = (int*)take(BATCH * sizeof(int));
    unsigned long long*  decKey   = (unsigned long long*)take((size_t)BATCH * NTOT * 8);
    float*               decC     = (float*)take((size_t)BATCH * NTOT * 4);
    float*               decB     = (float*)take((size_t)BATCH * NTOT * 16);
    float*               selS     = (float*)take((size_t)BATCH * NSEL * 4);
    int*                 selG     = (int*)take((size_t)BATCH * NSEL * 4);
    float*               selC     = (float*)take((size_t)BATCH * NSEL * 4);
    float*               selB     = (float*)take((size_t)BATCH * NSEL * 16);
    float*               srtS     = (float*)take((size_t)BATCH * NSEL * 4);
    float*               srtC     = (float*)take((size_t)BATCH * NSEL * 4);
    float*               srtB     = (float*)take((size_t)BATCH * NSEL * 16);
    unsigned long long*  gmask    = (unsigned long long*)take((size_t)BATCH * NSEL * WPR * 8 + 256);

    int totalDec = BATCH * NTOT; // 181944
    k_decode<<<(totalDec + 255) / 256, 256, 0, stream>>>(
        obj[0], reg[0], cls[0], anc[0],
        obj[1], reg[1], cls[1], anc[1],
        obj[2], reg[2], cls[2], anc[2],
        decKey, decC, decB, counters);

    k_select<<<BATCH * 3, 1024, 0, stream>>>(decKey, decC, decB,
                                             selS, selG, selC, selB, counters);

    k_rank_all<<<BATCH * 12, 256, 0, stream>>>(selS, selG, selC, selB,
                                               srtS, srtC, srtB);

    constexpr int TPB = (NSEL + 63) / 64; // 47
    k_iou<<<BATCH * TPB, 256, 0, stream>>>(srtB, gmask);

    k_resolve<<<BATCH, 256, 0, stream>>>(srtS, srtC, srtB, gmask, (float*)d_out);
}

// Round 4
// 224.196 us; speedup vs baseline: 5.5768x; 1.5710x over previous
//
#include <hip/hip_runtime.h>
#include <math.h>

// ---------------- problem constants ----------------
constexpr int BATCH   = 8;
constexpr int NUM_CLS = 80;
constexpr int N0 = 19 * 19 * 3;   // 1083  (stride 32)
constexpr int N1 = 38 * 38 * 3;   // 4332  (stride 16)
constexpr int N2 = 76 * 76 * 3;   // 17328 (stride 8)
constexpr int OFF1 = N0;          // 1083
constexpr int OFF2 = N0 + N1;     // 5415
constexpr int NTOT = N0 + N1 + N2; // 22743 per image
constexpr int TOPN = 1000;
constexpr int NSEL = 3 * TOPN;    // 3000 per image
constexpr int MAXDET = 100;
constexpr float MIN_SCORE_F = 0.05f;
constexpr int IMG_MAX = 607;
constexpr int WPR = (NSEL + 63) / 64; // 47 u64 words per mask row

__device__ __forceinline__ float sigmoidf_(float x) {
    return 1.0f / (1.0f + expf(-x));
}

// ---------------- K1: decode all candidates ----------------
__global__ __launch_bounds__(256) void k_decode(
    const float* __restrict__ obj0, const float* __restrict__ reg0,
    const float* __restrict__ cls0, const float* __restrict__ anc0,
    const float* __restrict__ obj1, const float* __restrict__ reg1,
    const float* __restrict__ cls1, const float* __restrict__ anc1,
    const float* __restrict__ obj2, const float* __restrict__ reg2,
    const float* __restrict__ cls2, const float* __restrict__ anc2,
    unsigned long long* __restrict__ decKey, float* __restrict__ decC,
    float* __restrict__ decB, int* __restrict__ gflagImg, int* __restrict__ fbCursor)
{
    if (blockIdx.x == 0 && threadIdx.x < 32) {
        if (threadIdx.x < 8)  gflagImg[threadIdx.x] = 0;
        if (threadIdx.x < 24) fbCursor[threadIdx.x] = 0;
    }
    int idx = blockIdx.x * 256 + threadIdx.x;
    if (idx >= BATCH * NTOT) return;
    int b  = idx / NTOT;
    int na = idx - b * NTOT;

    const float *obj, *reg, *cls, *anc;
    int Nl, n;
    if (na < OFF1)      { obj = obj0; reg = reg0; cls = cls0; anc = anc0; Nl = N0; n = na; }
    else if (na < OFF2) { obj = obj1; reg = reg1; cls = cls1; anc = anc1; Nl = N1; n = na - OFF1; }
    else                { obj = obj2; reg = reg2; cls = cls2; anc = anc2; Nl = N2; n = na - OFF2; }

    size_t bn = (size_t)b * Nl + n;

    float so = sigmoidf_(obj[bn]);

    const float4* cv = reinterpret_cast<const float4*>(cls + bn * NUM_CLS);
    float best = -1.0f; int bc = 0;
    #pragma unroll 4
    for (int t = 0; t < NUM_CLS / 4; ++t) {
        float4 v = cv[t];
        float s;
        s = sigmoidf_(v.x); if (s > best) { best = s; bc = 4 * t + 0; }
        s = sigmoidf_(v.y); if (s > best) { best = s; bc = 4 * t + 1; }
        s = sigmoidf_(v.z); if (s > best) { best = s; bc = 4 * t + 2; }
        s = sigmoidf_(v.w); if (s > best) { best = s; bc = 4 * t + 3; }
    }
    float score = best * so;

    float4 rv = reinterpret_cast<const float4*>(reg)[bn];
    const float* av = anc + bn * 5;
    float ax = av[0], ay = av[1], aw = av[2], ah = av[3], st = av[4];
    float cx = (sigmoidf_(rv.x) + ax) * st;
    float cy = (sigmoidf_(rv.y) + ay) * st;
    float w  = expf(rv.z) * aw / st;
    float h  = expf(rv.w) * ah / st;
    float x1f = cx - 0.5f * w;
    float y1f = cy - 0.5f * h;
    float x2f = w + x1f;
    float y2f = h + y1f;
    int x1 = (int)x1f, y1 = (int)y1f, x2 = (int)x2f, y2 = (int)y2f;
    x1 = (x1 < 0) ? 0 : x1;
    y1 = (y1 < 0) ? 0 : y1;
    x2 = (x2 > IMG_MAX) ? IMG_MAX : x2;
    y2 = (y2 > IMG_MAX) ? IMG_MAX : y2;

    size_t g = (size_t)b * NTOT + na;
    // key = raw score bits << 15 | (Nl - n): strict total order == top_k order
    decKey[g] = ((unsigned long long)__float_as_uint(score) << 15) | (unsigned)(Nl - n);
    decC[g] = (float)bc;
    reinterpret_cast<float4*>(decB)[g] =
        make_float4((float)x1, (float)y1, (float)x2, (float)y2);
}

// ---------------- K2: exact per-level top-1000, PLACED IN SORTED ORDER -------
// 4096-bin histogram over key>>33 (score top bits) -> suffix scan (cum[bin] =
// #keys in strictly-higher bins) -> scatter buckets intersecting the top-1000
// into LDS -> exact rank = cum[bin] + within-bucket count of greater keys.
// Writes selS/C/B/Key at slot lvl*1000 + rank. Overflow-safe fallback emits
// the exact top-1000 set unordered and raises gflagImg (k_merge then uses the
// O(N^2) rank path).
constexpr int NBIN  = 4096;
constexpr int STCAP = 2048;

__global__ __launch_bounds__(1024) void k_select(
    const unsigned long long* __restrict__ decKey, const float* __restrict__ decC,
    const float* __restrict__ decB, float* __restrict__ selS, float* __restrict__ selC,
    float* __restrict__ selB, unsigned long long* __restrict__ selKey,
    int* __restrict__ gflagImg, int* __restrict__ fbCursor)
{
    __shared__ unsigned hist[NBIN];            // counts, then per-bucket cursor/cnt
    __shared__ unsigned cum[NBIN];             // strictly-higher counts
    __shared__ unsigned chunkH[NBIN / 64];     // 64
    __shared__ unsigned long long stKey[STCAP];
    __shared__ int stIdx[STCAP];
    __shared__ int sTot; __shared__ int sOvf;
    __shared__ int sBstar; __shared__ int sNeed;

    int b   = blockIdx.x / 3;
    int lvl = blockIdx.x % 3;
    int off = (lvl == 0) ? 0 : (lvl == 1) ? OFF1 : OFF2;
    int Nl  = (lvl == 0) ? N0 : (lvl == 1) ? N1 : N2;
    int tid = threadIdx.x;

    const unsigned long long* keys = decKey + (size_t)b * NTOT + off;

    for (int t = tid; t < NBIN; t += 1024) hist[t] = 0;
    if (tid == 0) { sTot = 0; sOvf = 0; }
    __syncthreads();

    for (int t = tid; t < Nl; t += 1024)
        atomicAdd(&hist[(unsigned)(keys[t] >> 33)], 1u);
    __syncthreads();

    if (tid < NBIN / 64) {
        unsigned s = 0;
        for (int j = 0; j < 64; ++j) s += hist[tid * 64 + j];
        chunkH[tid] = s;
    }
    __syncthreads();
    if (tid == 0) {
        unsigned run = 0;
        for (int c = NBIN / 64 - 1; c >= 0; --c) {
            unsigned t = chunkH[c]; chunkH[c] = run; run += t;
        }
    }
    __syncthreads();
    if (tid < NBIN / 64) {
        unsigned run = chunkH[tid];
        for (int q = 63; q >= 0; --q) {
            cum[tid * 64 + q] = run;
            run += hist[tid * 64 + q];
        }
    }
    __syncthreads();

    for (int t = tid; t < NBIN; t += 1024) hist[t] = 0; // becomes cursor/cnt
    __syncthreads();

    for (int t = tid; t < Nl; t += 1024) {
        unsigned long long k = keys[t];
        unsigned bin = (unsigned)(k >> 33);
        if (cum[bin] < (unsigned)TOPN) {
            unsigned c = atomicAdd(&hist[bin], 1u);
            unsigned p = cum[bin] + c;
            atomicAdd(&sTot, 1);
            if (p < STCAP) { stKey[p] = k; stIdx[p] = t; }
            else sOvf = 1;
        }
    }
    __syncthreads();

    auto writeOut = [&](int t, int r) {
        size_t g = (size_t)b * NTOT + off + t;
        unsigned long long k = keys[t];
        float sraw = __uint_as_float((unsigned)(k >> 15));
        float strn = (sraw > MIN_SCORE_F) ? sraw : -1.0f;
        int G = off + t;
        // raw-score global key: order among score<=0.05 entries differs from ref
        // but is provably irrelevant (they never keep/suppress/output).
        unsigned long long gk =
            ((unsigned long long)(__float_as_uint(sraw) | 0x80000000u) << 16) |
            (unsigned)(NTOT - G);
        int o = b * NSEL + lvl * TOPN + r;
        selS[o] = strn;
        selC[o] = decC[g];
        selKey[o] = gk;
        reinterpret_cast<float4*>(selB)[o] = reinterpret_cast<const float4*>(decB)[g];
    };

    if (sOvf == 0) {
        int M = sTot;
        for (int p = tid; p < M; p += 1024) {
            unsigned long long k = stKey[p];
            unsigned bin = (unsigned)(k >> 33);
            unsigned start = cum[bin], end = start + hist[bin];
            int r = (int)start;
            for (unsigned q = start; q < end; ++q) r += (stKey[q] > k) ? 1 : 0;
            if (r < TOPN) writeOut(stIdx[p], r);
        }
    } else {
        // -------- never-expected exact fallback --------
        if (tid == 0) {
            gflagImg[b] = 1;
            int B = 0;
            for (int bin = NBIN - 1; bin >= 0; --bin) {
                if (cum[bin] <= (unsigned)(TOPN - 1) &&
                    cum[bin] + hist[bin] > (unsigned)(TOPN - 1)) { B = bin; break; }
            }
            sBstar = B; sNeed = TOPN - (int)cum[B];
        }
        __syncthreads();
        int Bstar = sBstar, need = sNeed;
        for (int t = tid; t < Nl; t += 1024) {
            unsigned long long k = keys[t];
            int bin = (int)(unsigned)(k >> 33);
            bool em = false;
            if (bin > Bstar) em = true;
            else if (bin == Bstar) {
                int r = 0;
                for (int j = 0; j < Nl; ++j) {
                    unsigned long long kj = keys[j];
                    r += ((int)(unsigned)(kj >> 33) == Bstar && kj > k) ? 1 : 0;
                }
                em = (r < need);
            }
            if (em) {
                int r = atomicAdd(&fbCursor[b * 3 + lvl], 1);
                writeOut(t, r);
            }
        }
    }
}

// ---------------- K3: merge 3 sorted lists -> global sorted order ------------
__global__ __launch_bounds__(1024) void k_merge(
    const float* __restrict__ selS, const float* __restrict__ selC,
    const float* __restrict__ selB, const unsigned long long* __restrict__ selKey,
    const int* __restrict__ gflagImg,
    float* __restrict__ srtS, float* __restrict__ srtC, float* __restrict__ srtB)
{
    __shared__ unsigned long long ks[NSEL]; // 24 KB
    int b = blockIdx.x, tid = threadIdx.x;
    for (int t = tid; t < NSEL; t += 1024) ks[t] = selKey[b * NSEL + t];
    __syncthreads();
    int fb = gflagImg[b];

    for (int t = tid; t < NSEL; t += 1024) {
        unsigned long long k = ks[t];
        int rank;
        if (!fb) {
            int l = t / TOPN;
            rank = t - l * TOPN;
            #pragma unroll
            for (int m = 0; m < 3; ++m) {
                if (m == l) continue;
                int base = m * TOPN, lo = 0, hi = TOPN;
                while (lo < hi) {
                    int mid = (lo + hi) >> 1;
                    if (ks[base + mid] > k) lo = mid + 1; else hi = mid;
                }
                rank += lo;
            }
        } else {
            int r = 0;
            for (int j = 0; j < NSEL; ++j) r += (ks[j] > k) ? 1 : 0;
            rank = r;
        }
        int o = b * NSEL + rank;
        srtS[o] = selS[b * NSEL + t];
        srtC[o] = selC[b * NSEL + t];
        reinterpret_cast<float4*>(srtB)[o] =
            reinterpret_cast<const float4*>(selB)[b * NSEL + t];
    }
}

// ---------------- K4a: pairwise suppression masks, register/ballot ----------
// One wave per 64x64 upper-triangle tile (9024 tasks, 2256 blocks). Lane owns
// column box j in registers; per row i: broadcast row box + ~15 VALU + ballot
// = the mask word. gmask layout column-major [b][w][i] -> coalesced stores.
// Sub-diagonal words (w < i>>6) are NOT written; k_resolve zeroes them at use.
constexpr int NTASK = WPR * (WPR + 1) / 2; // 1128 per image

__global__ __launch_bounds__(256) void k_iou(
    const float* __restrict__ srtB, unsigned long long* __restrict__ gmask)
{
    int wtask = blockIdx.x * 4 + (threadIdx.x >> 6);
    if (wtask >= BATCH * NTASK) return;
    int b = wtask / NTASK;
    int u = wtask % NTASK;
    int r = 0;
    while (u >= WPR - r) { u -= WPR - r; r++; }
    int w = r + u;

    int lane = threadIdx.x & 63;
    int jIdx = w * 64 + lane;
    const float4* Bx = reinterpret_cast<const float4*>(srtB) + (size_t)b * NSEL;

    float4 bj = (jIdx < NSEL) ? Bx[jIdx]
                              : make_float4(4e8f, 4e8f, -4e8f, -4e8f); // never intersects
    float aj = (bj.z - bj.x) * (bj.w - bj.y);

    unsigned long long rowWord = 0ull;
    int rowBase = r * 64;
    #pragma unroll 8
    for (int it = 0; it < 64; ++it) {
        int i = rowBase + it;
        int iS = (i < NSEL) ? i : 0;
        float4 bi = Bx[iS];
        float ai = (bi.z - bi.x) * (bi.w - bi.y);
        float xx1 = fmaxf(bi.x, bj.x);
        float yy1 = fmaxf(bi.y, bj.y);
        float xx2 = fminf(bi.z, bj.z);
        float yy2 = fminf(bi.w, bj.w);
        float inter = fmaxf(xx2 - xx1, 0.0f) * fmaxf(yy2 - yy1, 0.0f);
        float uni = ai + aj - inter;
        // exact vs iou>0.5: inter/uni are exact ints < 2^20 in fp32
        bool sup = (inter > 0.5f * uni) && (inter > 0.0f) && (jIdx > i);
        unsigned long long word = __ballot(sup);
        if (lane == it) rowWord = word;
    }
    int i = rowBase + lane;
    if (i < NSEL)
        gmask[((size_t)b * WPR + w) * NSEL + i] = rowWord;
}

// ---------------- K4b: greedy resolve, one block per image -------------------
constexpr int RTILE = 256;

__global__ __launch_bounds__(256) void k_resolve(
    const float* __restrict__ srtS, const float* __restrict__ srtC,
    const float* __restrict__ srtB, const unsigned long long* __restrict__ gmask,
    float* __restrict__ out)
{
    __shared__ unsigned long long tileM[RTILE * WPR]; // 94 KB
    __shared__ unsigned long long validLds[WPR];
    __shared__ int keptIdx[MAXDET];
    __shared__ int sPos;

    int b = blockIdx.x, tid = threadIdx.x;
    const unsigned long long* gm = gmask + (size_t)b * WPR * NSEL;
    const float* S = srtS + b * NSEL;

    // stage first RTILE rows (column-major global -> row-major LDS), coalesced
    for (int t = tid; t < RTILE * WPR; t += 256) {
        int w  = t >> 8;          // t / 256
        int rr = t & 255;
        tileM[rr * WPR + w] = gm[(size_t)w * NSEL + rr];
    }

    for (int k = 0; k < 12; ++k) {
        int j = k * 256 + tid;
        float s = (j < NSEL) ? S[j] : -1.0f;
        unsigned long long bal = __ballot(s > MIN_SCORE_F);
        int wIdx = k * 4 + (tid >> 6);
        if ((tid & 63) == 0 && wIdx < WPR) validLds[wIdx] = bal;
    }
    __syncthreads();

    if (tid < 64) {
        int lane = tid;
        unsigned long long validw = (lane < WPR) ? validLds[lane] : 0ull;
        unsigned long long removed = 0ull;
        int pos = 0;
        int curw = 0;
        while (true) {
            unsigned long long avail = validw & ~removed;
            unsigned long long bal = __ballot(lane >= curw && avail != 0ull);
            if (bal == 0ull) break;
            int fw = __ffsll(bal) - 1;
            unsigned long long wbits = __shfl(avail, fw);
            int bit = __ffsll(wbits) - 1;
            int i = fw * 64 + bit;
            if (lane == 0) keptIdx[pos] = i;
            pos++;
            if (pos >= MAXDET) break;
            if (lane == fw) validw &= ~(1ull << bit);
            unsigned long long m = 0ull;
            if (lane < WPR) {
                m = (i < RTILE) ? tileM[i * WPR + lane]
                                : gm[(size_t)lane * NSEL + i];
                if (lane < (i >> 6)) m = 0ull; // sub-diagonal words unwritten
            }
            removed |= m;
            curw = fw;
        }
        if (lane == 0) sPos = pos;
    }
    __syncthreads();

    int pos = sPos;
    const float*  C  = srtC + b * NSEL;
    const float4* Bx = reinterpret_cast<const float4*>(srtB) + (size_t)b * NSEL;
    float* out_s = out + b * MAXDET;
    float* out_c = out + BATCH * MAXDET + b * MAXDET;
    float* out_b = out + 2 * BATCH * MAXDET + (size_t)b * MAXDET * 4;
    for (int t = tid; t < MAXDET; t += 256) {
        if (t < pos) {
            int ki = keptIdx[t];
            float4 bb = Bx[ki];
            out_s[t] = S[ki];
            out_c[t] = C[ki];
            out_b[t * 4 + 0] = bb.x; out_b[t * 4 + 1] = bb.y;
            out_b[t * 4 + 2] = bb.z; out_b[t * 4 + 3] = bb.w;
        } else {
            out_s[t] = -1.0f; out_c[t] = -1.0f;
            out_b[t * 4 + 0] = -1.0f; out_b[t * 4 + 1] = -1.0f;
            out_b[t * 4 + 2] = -1.0f; out_b[t * 4 + 3] = -1.0f;
        }
    }
}

// ---------------- host launcher ----------------
extern "C" void kernel_launch(void* const* d_in, const int* in_sizes, int n_in,
                              void* d_out, int out_size, void* d_ws, size_t ws_size,
                              hipStream_t stream) {
    (void)n_in; (void)out_size; (void)ws_size;

    bool dict = (in_sizes[2] == BATCH * N0 * NUM_CLS); // 693120
    const float *obj[3], *reg[3], *cls[3], *anc[3];
    for (int l = 0; l < 3; ++l) {
        obj[l] = (const float*)d_in[dict ? 4 * l + 0 : l];
        reg[l] = (const float*)d_in[dict ? 4 * l + 1 : 3 + l];
        cls[l] = (const float*)d_in[dict ? 4 * l + 2 : 6 + l];
        anc[l] = (const float*)d_in[dict ? 4 * l + 3 : 9 + l];
    }

    char* ws = (char*)d_ws;
    size_t off = 0;
    auto take = [&](size_t bytes) -> void* {
        void* p = ws + off;
        off += (bytes + 255) & ~(size_t)255;
        return p;
    };
    int*                 gflagImg = (int*)take(BATCH * sizeof(int));
    int*                 fbCursor = (int*)take(BATCH * 3 * sizeof(int));
    unsigned long long*  decKey   = (unsigned long long*)take((size_t)BATCH * NTOT * 8);
    float*               decC     = (float*)take((size_t)BATCH * NTOT * 4);
    float*               decB     = (float*)take((size_t)BATCH * NTOT * 16);
    float*               selS     = (float*)take((size_t)BATCH * NSEL * 4);
    float*               selC     = (float*)take((size_t)BATCH * NSEL * 4);
    float*               selB     = (float*)take((size_t)BATCH * NSEL * 16);
    unsigned long long*  selKey   = (unsigned long long*)take((size_t)BATCH * NSEL * 8);
    float*               srtS     = (float*)take((size_t)BATCH * NSEL * 4);
    float*               srtC     = (float*)take((size_t)BATCH * NSEL * 4);
    float*               srtB     = (float*)take((size_t)BATCH * NSEL * 16);
    unsigned long long*  gmask    = (unsigned long long*)take((size_t)BATCH * WPR * NSEL * 8 + 256);

    int totalDec = BATCH * NTOT; // 181944
    k_decode<<<(totalDec + 255) / 256, 256, 0, stream>>>(
        obj[0], reg[0], cls[0], anc[0],
        obj[1], reg[1], cls[1], anc[1],
        obj[2], reg[2], cls[2], anc[2],
        decKey, decC, decB, gflagImg, fbCursor);

    k_select<<<BATCH * 3, 1024, 0, stream>>>(decKey, decC, decB,
                                             selS, selC, selB, selKey,
                                             gflagImg, fbCursor);

    k_merge<<<BATCH, 1024, 0, stream>>>(selS, selC, selB, selKey, gflagImg,
                                        srtS, srtC, srtB);

    int nIouBlocks = (BATCH * NTASK + 3) / 4; // 2256
    k_iou<<<nIouBlocks, 256, 0, stream>>>(srtB, gmask);

    k_resolve<<<BATCH, 256, 0, stream>>>(srtS, srtC, srtB, gmask, (float*)d_out);
}

// Round 5
// 214.965 us; speedup vs baseline: 5.8163x; 1.0429x over previous
//
#include <hip/hip_runtime.h>
#include <math.h>

// ---------------- problem constants ----------------
constexpr int BATCH   = 8;
constexpr int NUM_CLS = 80;
constexpr int N0 = 19 * 19 * 3;   // 1083  (stride 32)
constexpr int N1 = 38 * 38 * 3;   // 4332  (stride 16)
constexpr int N2 = 76 * 76 * 3;   // 17328 (stride 8)
constexpr int OFF1 = N0;          // 1083
constexpr int OFF2 = N0 + N1;     // 5415
constexpr int NTOT = N0 + N1 + N2; // 22743 per image
constexpr int TOPN = 1000;
constexpr int NSEL = 3 * TOPN;    // 3000 per image
constexpr int MAXDET = 100;
constexpr float MIN_SCORE_F = 0.05f;
constexpr int IMG_MAX = 607;
constexpr int WPR = (NSEL + 63) / 64; // 47 u64 words per mask row

__device__ __forceinline__ float sigmoidf_(float x) {
    return 1.0f / (1.0f + expf(-x));
}

// ---------------- K1: decode all candidates ----------------
__global__ __launch_bounds__(256) void k_decode(
    const float* __restrict__ obj0, const float* __restrict__ reg0,
    const float* __restrict__ cls0, const float* __restrict__ anc0,
    const float* __restrict__ obj1, const float* __restrict__ reg1,
    const float* __restrict__ cls1, const float* __restrict__ anc1,
    const float* __restrict__ obj2, const float* __restrict__ reg2,
    const float* __restrict__ cls2, const float* __restrict__ anc2,
    unsigned long long* __restrict__ decKey, float* __restrict__ decC,
    float* __restrict__ decB, int* __restrict__ gflagImg, int* __restrict__ fbCursor)
{
    if (blockIdx.x == 0 && threadIdx.x < 32) {
        if (threadIdx.x < 8)  gflagImg[threadIdx.x] = 0;
        if (threadIdx.x < 24) fbCursor[threadIdx.x] = 0;
    }
    int idx = blockIdx.x * 256 + threadIdx.x;
    if (idx >= BATCH * NTOT) return;
    int b  = idx / NTOT;
    int na = idx - b * NTOT;

    const float *obj, *reg, *cls, *anc;
    int Nl, n;
    if (na < OFF1)      { obj = obj0; reg = reg0; cls = cls0; anc = anc0; Nl = N0; n = na; }
    else if (na < OFF2) { obj = obj1; reg = reg1; cls = cls1; anc = anc1; Nl = N1; n = na - OFF1; }
    else                { obj = obj2; reg = reg2; cls = cls2; anc = anc2; Nl = N2; n = na - OFF2; }

    size_t bn = (size_t)b * Nl + n;

    float so = sigmoidf_(obj[bn]);

    const float4* cv = reinterpret_cast<const float4*>(cls + bn * NUM_CLS);
    float best = -1.0f; int bc = 0;
    #pragma unroll 4
    for (int t = 0; t < NUM_CLS / 4; ++t) {
        float4 v = cv[t];
        float s;
        s = sigmoidf_(v.x); if (s > best) { best = s; bc = 4 * t + 0; }
        s = sigmoidf_(v.y); if (s > best) { best = s; bc = 4 * t + 1; }
        s = sigmoidf_(v.z); if (s > best) { best = s; bc = 4 * t + 2; }
        s = sigmoidf_(v.w); if (s > best) { best = s; bc = 4 * t + 3; }
    }
    float score = best * so;

    float4 rv = reinterpret_cast<const float4*>(reg)[bn];
    const float* av = anc + bn * 5;
    float ax = av[0], ay = av[1], aw = av[2], ah = av[3], st = av[4];
    float cx = (sigmoidf_(rv.x) + ax) * st;
    float cy = (sigmoidf_(rv.y) + ay) * st;
    float w  = expf(rv.z) * aw / st;
    float h  = expf(rv.w) * ah / st;
    float x1f = cx - 0.5f * w;
    float y1f = cy - 0.5f * h;
    float x2f = w + x1f;
    float y2f = h + y1f;
    int x1 = (int)x1f, y1 = (int)y1f, x2 = (int)x2f, y2 = (int)y2f;
    x1 = (x1 < 0) ? 0 : x1;
    y1 = (y1 < 0) ? 0 : y1;
    x2 = (x2 > IMG_MAX) ? IMG_MAX : x2;
    y2 = (y2 > IMG_MAX) ? IMG_MAX : y2;

    size_t g = (size_t)b * NTOT + na;
    // key = raw score bits << 15 | (Nl - n): strict total order == top_k order
    decKey[g] = ((unsigned long long)__float_as_uint(score) << 15) | (unsigned)(Nl - n);
    decC[g] = (float)bc;
    reinterpret_cast<float4*>(decB)[g] =
        make_float4((float)x1, (float)y1, (float)x2, (float)y2);
}

// ---------------- K2: exact per-level top-1000, PLACED IN SORTED ORDER -------
constexpr int NBIN  = 4096;
constexpr int STCAP = 2048;

__global__ __launch_bounds__(1024) void k_select(
    const unsigned long long* __restrict__ decKey, const float* __restrict__ decC,
    const float* __restrict__ decB, float* __restrict__ selS, float* __restrict__ selC,
    float* __restrict__ selB, unsigned long long* __restrict__ selKey,
    int* __restrict__ gflagImg, int* __restrict__ fbCursor)
{
    __shared__ unsigned hist[NBIN];            // counts, then per-bucket cursor/cnt
    __shared__ unsigned cum[NBIN];             // strictly-higher counts
    __shared__ unsigned chunkH[NBIN / 64];     // 64
    __shared__ unsigned long long stKey[STCAP];
    __shared__ int stIdx[STCAP];
    __shared__ int sTot; __shared__ int sOvf;
    __shared__ int sBstar; __shared__ int sNeed;

    int b   = blockIdx.x / 3;
    int lvl = blockIdx.x % 3;
    int off = (lvl == 0) ? 0 : (lvl == 1) ? OFF1 : OFF2;
    int Nl  = (lvl == 0) ? N0 : (lvl == 1) ? N1 : N2;
    int tid = threadIdx.x;

    const unsigned long long* keys = decKey + (size_t)b * NTOT + off;

    for (int t = tid; t < NBIN; t += 1024) hist[t] = 0;
    if (tid == 0) { sTot = 0; sOvf = 0; }
    __syncthreads();

    for (int t = tid; t < Nl; t += 1024)
        atomicAdd(&hist[(unsigned)(keys[t] >> 33)], 1u);
    __syncthreads();

    if (tid < NBIN / 64) {
        unsigned s = 0;
        for (int j = 0; j < 64; ++j) s += hist[tid * 64 + j];
        chunkH[tid] = s;
    }
    __syncthreads();
    if (tid == 0) {
        unsigned run = 0;
        for (int c = NBIN / 64 - 1; c >= 0; --c) {
            unsigned t = chunkH[c]; chunkH[c] = run; run += t;
        }
    }
    __syncthreads();
    if (tid < NBIN / 64) {
        unsigned run = chunkH[tid];
        for (int q = 63; q >= 0; --q) {
            cum[tid * 64 + q] = run;
            run += hist[tid * 64 + q];
        }
    }
    __syncthreads();

    for (int t = tid; t < NBIN; t += 1024) hist[t] = 0; // becomes cursor/cnt
    __syncthreads();

    for (int t = tid; t < Nl; t += 1024) {
        unsigned long long k = keys[t];
        unsigned bin = (unsigned)(k >> 33);
        if (cum[bin] < (unsigned)TOPN) {
            unsigned c = atomicAdd(&hist[bin], 1u);
            unsigned p = cum[bin] + c;
            atomicAdd(&sTot, 1);
            if (p < STCAP) { stKey[p] = k; stIdx[p] = t; }
            else sOvf = 1;
        }
    }
    __syncthreads();

    auto writeOut = [&](int t, int r) {
        size_t g = (size_t)b * NTOT + off + t;
        unsigned long long k = keys[t];
        float sraw = __uint_as_float((unsigned)(k >> 15));
        float strn = (sraw > MIN_SCORE_F) ? sraw : -1.0f;
        int G = off + t;
        // raw-score global key: order among score<=0.05 entries differs from ref
        // but is provably irrelevant (they never keep/suppress/output).
        unsigned long long gk =
            ((unsigned long long)(__float_as_uint(sraw) | 0x80000000u) << 16) |
            (unsigned)(NTOT - G);
        int o = b * NSEL + lvl * TOPN + r;
        selS[o] = strn;
        selC[o] = decC[g];
        selKey[o] = gk;
        reinterpret_cast<float4*>(selB)[o] = reinterpret_cast<const float4*>(decB)[g];
    };

    if (sOvf == 0) {
        int M = sTot;
        for (int p = tid; p < M; p += 1024) {
            unsigned long long k = stKey[p];
            unsigned bin = (unsigned)(k >> 33);
            unsigned start = cum[bin], end = start + hist[bin];
            int r = (int)start;
            for (unsigned q = start; q < end; ++q) r += (stKey[q] > k) ? 1 : 0;
            if (r < TOPN) writeOut(stIdx[p], r);
        }
    } else {
        // -------- never-expected exact fallback --------
        if (tid == 0) {
            gflagImg[b] = 1;
            int B = 0;
            for (int bin = NBIN - 1; bin >= 0; --bin) {
                if (cum[bin] <= (unsigned)(TOPN - 1) &&
                    cum[bin] + hist[bin] > (unsigned)(TOPN - 1)) { B = bin; break; }
            }
            sBstar = B; sNeed = TOPN - (int)cum[B];
        }
        __syncthreads();
        int Bstar = sBstar, need = sNeed;
        for (int t = tid; t < Nl; t += 1024) {
            unsigned long long k = keys[t];
            int bin = (int)(unsigned)(k >> 33);
            bool em = false;
            if (bin > Bstar) em = true;
            else if (bin == Bstar) {
                int r = 0;
                for (int j = 0; j < Nl; ++j) {
                    unsigned long long kj = keys[j];
                    r += ((int)(unsigned)(kj >> 33) == Bstar && kj > k) ? 1 : 0;
                }
                em = (r < need);
            }
            if (em) {
                int r = atomicAdd(&fbCursor[b * 3 + lvl], 1);
                writeOut(t, r);
            }
        }
    }
}

// ---------------- K3: merge 3 sorted lists -> global sorted order ------------
__global__ __launch_bounds__(1024) void k_merge(
    const float* __restrict__ selS, const float* __restrict__ selC,
    const float* __restrict__ selB, const unsigned long long* __restrict__ selKey,
    const int* __restrict__ gflagImg,
    float* __restrict__ srtS, float* __restrict__ srtC, float* __restrict__ srtB)
{
    __shared__ unsigned long long ks[NSEL]; // 24 KB
    int b = blockIdx.x, tid = threadIdx.x;
    for (int t = tid; t < NSEL; t += 1024) ks[t] = selKey[b * NSEL + t];
    __syncthreads();
    int fb = gflagImg[b];

    for (int t = tid; t < NSEL; t += 1024) {
        unsigned long long k = ks[t];
        int rank;
        if (!fb) {
            int l = t / TOPN;
            rank = t - l * TOPN;
            #pragma unroll
            for (int m = 0; m < 3; ++m) {
                if (m == l) continue;
                int base = m * TOPN, lo = 0, hi = TOPN;
                while (lo < hi) {
                    int mid = (lo + hi) >> 1;
                    if (ks[base + mid] > k) lo = mid + 1; else hi = mid;
                }
                rank += lo;
            }
        } else {
            int r = 0;
            for (int j = 0; j < NSEL; ++j) r += (ks[j] > k) ? 1 : 0;
            rank = r;
        }
        int o = b * NSEL + rank;
        srtS[o] = selS[b * NSEL + t];
        srtC[o] = selC[b * NSEL + t];
        reinterpret_cast<float4*>(srtB)[o] =
            reinterpret_cast<const float4*>(selB)[b * NSEL + t];
    }
}

// ---------------- K4a: pairwise suppression masks, register/ballot ----------
// One wave per 64x64 upper-triangle tile. Lane owns column box j in registers;
// per row i: broadcast row box + ~15 VALU + ballot = the mask word. gmask is
// column-major [b][w][i] -> coalesced stores. Sub-diagonal words (w < i>>6)
// are NOT written; k_resolve zeroes them at use.
constexpr int NTASK = WPR * (WPR + 1) / 2; // 1128 per image

__global__ __launch_bounds__(256) void k_iou(
    const float* __restrict__ srtB, unsigned long long* __restrict__ gmask)
{
    int wtask = blockIdx.x * 4 + (threadIdx.x >> 6);
    if (wtask >= BATCH * NTASK) return;
    int b = wtask / NTASK;
    int u = wtask % NTASK;
    int r = 0;
    while (u >= WPR - r) { u -= WPR - r; r++; }
    int w = r + u;

    int lane = threadIdx.x & 63;
    int jIdx = w * 64 + lane;
    const float4* Bx = reinterpret_cast<const float4*>(srtB) + (size_t)b * NSEL;

    float4 bj = (jIdx < NSEL) ? Bx[jIdx]
                              : make_float4(4e8f, 4e8f, -4e8f, -4e8f); // never intersects
    float aj = (bj.z - bj.x) * (bj.w - bj.y);

    unsigned long long rowWord = 0ull;
    int rowBase = r * 64;
    #pragma unroll 8
    for (int it = 0; it < 64; ++it) {
        int i = rowBase + it;
        int iS = (i < NSEL) ? i : 0;
        float4 bi = Bx[iS];
        float ai = (bi.z - bi.x) * (bi.w - bi.y);
        float xx1 = fmaxf(bi.x, bj.x);
        float yy1 = fmaxf(bi.y, bj.y);
        float xx2 = fminf(bi.z, bj.z);
        float yy2 = fminf(bi.w, bj.w);
        float inter = fmaxf(xx2 - xx1, 0.0f) * fmaxf(yy2 - yy1, 0.0f);
        float uni = ai + aj - inter;
        // exact vs iou>0.5: inter/uni are exact ints < 2^20 in fp32
        bool sup = (inter > 0.5f * uni) && (inter > 0.0f) && (jIdx > i);
        unsigned long long word = __ballot(sup);
        if (lane == it) rowWord = word;
    }
    int i = rowBase + lane;
    if (i < NSEL)
        gmask[((size_t)b * WPR + w) * NSEL + i] = rowWord;
}

// ---------------- K4b: greedy resolve with batched speculative prefetch ------
// One wave per image does the serial greedy walk. Per round: pick the first
// WIN available candidates from the register bitmap (ballot/ffs only), gather
// all WIN mask rows concurrently (one memory round trip), then apply greedily
// within the window (a candidate is kept iff its avail bit survived the rows
// applied so far). Exactly greedy: avail only loses bits, window = first-WIN
// avail at round start. Every window slot is consumed -> guaranteed progress.
constexpr int WIN = 8;

__global__ __launch_bounds__(256) void k_resolve(
    const float* __restrict__ srtS, const float* __restrict__ srtC,
    const float* __restrict__ srtB, const unsigned long long* __restrict__ gmask,
    float* __restrict__ out)
{
    __shared__ unsigned long long validLds[WPR];
    __shared__ int keptIdx[MAXDET];
    __shared__ int sPos;

    int b = blockIdx.x, tid = threadIdx.x;
    const unsigned long long* gm = gmask + (size_t)b * WPR * NSEL;
    const float* S = srtS + b * NSEL;

    // valid bitmap: wave w's ballot at iteration k covers word k*4+w
    for (int k = 0; k < 12; ++k) {
        int j = k * 256 + tid;
        float s = (j < NSEL) ? S[j] : -1.0f;
        unsigned long long bal = __ballot(s > MIN_SCORE_F);
        int wIdx = k * 4 + (tid >> 6);
        if ((tid & 63) == 0 && wIdx < WPR) validLds[wIdx] = bal;
    }
    __syncthreads();

    if (tid < 64) {
        int lane = tid;
        unsigned long long validw = (lane < WPR) ? validLds[lane] : 0ull;
        unsigned long long removed = 0ull;
        int pos = 0;
        bool done = false;
        while (!done) {
            // ---- pick first WIN avail candidates (uniform, register-only) ----
            unsigned long long tmp = validw & ~removed;
            int c[WIN];
            int nc = 0;
            #pragma unroll
            for (int k = 0; k < WIN; ++k) {
                unsigned long long bal = __ballot(tmp != 0ull);
                if (bal == 0ull) break;            // uniform
                int fw = __ffsll(bal) - 1;
                unsigned long long wb = __shfl(tmp, fw);
                int bit = __ffsll(wb) - 1;
                c[k] = fw * 64 + bit;
                nc = k + 1;
                if (lane == fw) tmp &= tmp - 1ull;  // clear lowest set bit
            }
            if (nc == 0) break;

            // ---- concurrent gather of all WIN mask rows (one round trip) ----
            unsigned long long mk[WIN];
            #pragma unroll
            for (int k = 0; k < WIN; ++k) {
                mk[k] = 0ull;
                if (k < nc && lane < WPR && lane >= (c[k] >> 6))
                    mk[k] = gm[(size_t)lane * NSEL + c[k]];
            }

            // ---- greedy apply within window ----
            #pragma unroll
            for (int k = 0; k < WIN; ++k) {
                if (k >= nc) break;
                int ck = c[k];
                unsigned long long availw = __shfl(validw & ~removed, ck >> 6);
                if ((availw >> (ck & 63)) & 1ull) {   // uniform
                    if (lane == 0) keptIdx[pos] = ck;
                    pos++;
                    if (lane == (ck >> 6)) validw &= ~(1ull << (ck & 63));
                    removed |= mk[k];
                    if (pos >= MAXDET) { done = true; break; }
                }
            }
        }
        if (lane == 0) sPos = pos;
    }
    __syncthreads();

    int pos = sPos;
    const float*  C  = srtC + b * NSEL;
    const float4* Bx = reinterpret_cast<const float4*>(srtB) + (size_t)b * NSEL;
    float* out_s = out + b * MAXDET;
    float* out_c = out + BATCH * MAXDET + b * MAXDET;
    float* out_b = out + 2 * BATCH * MAXDET + (size_t)b * MAXDET * 4;
    for (int t = tid; t < MAXDET; t += 256) {
        if (t < pos) {
            int ki = keptIdx[t];
            float4 bb = Bx[ki];
            out_s[t] = S[ki];
            out_c[t] = C[ki];
            out_b[t * 4 + 0] = bb.x; out_b[t * 4 + 1] = bb.y;
            out_b[t * 4 + 2] = bb.z; out_b[t * 4 + 3] = bb.w;
        } else {
            out_s[t] = -1.0f; out_c[t] = -1.0f;
            out_b[t * 4 + 0] = -1.0f; out_b[t * 4 + 1] = -1.0f;
            out_b[t * 4 + 2] = -1.0f; out_b[t * 4 + 3] = -1.0f;
        }
    }
}

// ---------------- host launcher ----------------
extern "C" void kernel_launch(void* const* d_in, const int* in_sizes, int n_in,
                              void* d_out, int out_size, void* d_ws, size_t ws_size,
                              hipStream_t stream) {
    (void)n_in; (void)out_size; (void)ws_size;

    bool dict = (in_sizes[2] == BATCH * N0 * NUM_CLS); // 693120
    const float *obj[3], *reg[3], *cls[3], *anc[3];
    for (int l = 0; l < 3; ++l) {
        obj[l] = (const float*)d_in[dict ? 4 * l + 0 : l];
        reg[l] = (const float*)d_in[dict ? 4 * l + 1 : 3 + l];
        cls[l] = (const float*)d_in[dict ? 4 * l + 2 : 6 + l];
        anc[l] = (const float*)d_in[dict ? 4 * l + 3 : 9 + l];
    }

    char* ws = (char*)d_ws;
    size_t off = 0;
    auto take = [&](size_t bytes) -> void* {
        void* p = ws + off;
        off += (bytes + 255) & ~(size_t)255;
        return p;
    };
    int*                 gflagImg = (int*)take(BATCH * sizeof(int));
    int*                 fbCursor = (int*)take(BATCH * 3 * sizeof(int));
    unsigned long long*  decKey   = (unsigned long long*)take((size_t)BATCH * NTOT * 8);
    float*               decC     = (float*)take((size_t)BATCH * NTOT * 4);
    float*               decB     = (float*)take((size_t)BATCH * NTOT * 16);
    float*               selS     = (float*)take((size_t)BATCH * NSEL * 4);
    float*               selC     = (float*)take((size_t)BATCH * NSEL * 4);
    float*               selB     = (float*)take((size_t)BATCH * NSEL * 16);
    unsigned long long*  selKey   = (unsigned long long*)take((size_t)BATCH * NSEL * 8);
    float*               srtS     = (float*)take((size_t)BATCH * NSEL * 4);
    float*               srtC     = (float*)take((size_t)BATCH * NSEL * 4);
    float*               srtB     = (float*)take((size_t)BATCH * NSEL * 16);
    unsigned long long*  gmask    = (unsigned long long*)take((size_t)BATCH * WPR * NSEL * 8 + 256);

    int totalDec = BATCH * NTOT; // 181944
    k_decode<<<(totalDec + 255) / 256, 256, 0, stream>>>(
        obj[0], reg[0], cls[0], anc[0],
        obj[1], reg[1], cls[1], anc[1],
        obj[2], reg[2], cls[2], anc[2],
        decKey, decC, decB, gflagImg, fbCursor);

    k_select<<<BATCH * 3, 1024, 0, stream>>>(decKey, decC, decB,
                                             selS, selC, selB, selKey,
                                             gflagImg, fbCursor);

    k_merge<<<BATCH, 1024, 0, stream>>>(selS, selC, selB, selKey, gflagImg,
                                        srtS, srtC, srtB);

    int nIouBlocks = (BATCH * NTASK + 3) / 4; // 2256
    k_iou<<<nIouBlocks, 256, 0, stream>>>(srtB, gmask);

    k_resolve<<<BATCH, 256, 0, stream>>>(srtS, srtC, srtB, gmask, (float*)d_out);
}